// Round 1
// baseline (371.418 us; speedup 1.0000x reference)
//
#include <hip/hip_runtime.h>
#include <hip/hip_bf16.h>

// ---------------------------------------------------------------------------
// ReyEquiv2to2: edge-feature MLP (4->128->128->128->2) over B*C*n*(n-1) rows,
// scatter/diag-reduce into out[B,C,64,64], then channel MLP 64->128->256->256->32.
// bf16 MFMA (16x16x32) for all big GEMMs, fp32 accumulate.
// ---------------------------------------------------------------------------

typedef __attribute__((ext_vector_type(4))) float f32x4;
typedef __attribute__((ext_vector_type(8))) short s16x8;

__device__ __forceinline__ short f2bf(float f) {
    unsigned int u = __builtin_bit_cast(unsigned int, f);
    u += 0x7fffu + ((u >> 16) & 1u);   // RNE
    return (short)(u >> 16);
}
__device__ __forceinline__ float bf2f(short s) {
    unsigned int u = ((unsigned int)(unsigned short)s) << 16;
    return __builtin_bit_cast(float, u);
}

// ---------------------------------------------------------------------------
// Weight prep: transpose to [n][k] bf16 so MFMA B-fragment reads are contiguous.
// ---------------------------------------------------------------------------
__global__ void k_prep(const float* __restrict__ W2, const float* __restrict__ W3,
                       const float* __restrict__ W4,
                       const float* __restrict__ Wc1, const float* __restrict__ Wc2,
                       const float* __restrict__ Wc3, const float* __restrict__ Wc4,
                       short* __restrict__ W2T, short* __restrict__ W3T,
                       float* __restrict__ W4T,
                       short* __restrict__ Wc1T, short* __restrict__ Wc2T,
                       short* __restrict__ Wc3T, short* __restrict__ Wc4T)
{
    int tid = blockIdx.x * 256 + threadIdx.x;   // grid covers 65536
    if (tid < 16384) {  // W2T/W3T: [n<128][k<128]
        int n = tid >> 7, k = tid & 127;
        W2T[tid] = f2bf(W2[k * 128 + n]);
        W3T[tid] = f2bf(W3[k * 128 + n]);
    }
    if (tid < 256) {    // W4T: [s<2][k<128] fp32
        int s = tid >> 7, k = tid & 127;
        W4T[tid] = W4[k * 2 + s];
    }
    if (tid < 8192) {   // Wc1T: [n<128][c<64]
        int n = tid >> 6, c = tid & 63;
        Wc1T[tid] = f2bf(Wc1[c * 128 + n]);
    }
    if (tid < 32768) {  // Wc2T: [n<256][k<128]
        int n = tid >> 7, k = tid & 127;
        Wc2T[tid] = f2bf(Wc2[k * 256 + n]);
    }
    if (tid < 65536) {  // Wc3T: [n<256][k<256]
        int n = tid >> 8, k = tid & 255;
        Wc3T[tid] = f2bf(Wc3[k * 256 + n]);
    }
    if (tid < 8192) {   // Wc4T: [n<32][k<256]
        int n = tid >> 8, k = tid & 255;
        Wc4T[tid] = f2bf(Wc4[k * 32 + n]);
    }
}

// ---------------------------------------------------------------------------
// Phase-1: one 128x128x128 bf16 MFMA layer (relu + store bf16 back to LDS).
// LDS tiles use XOR swizzle: byte ^= (row&7)<<4  (kills 256B-stride conflicts)
// ---------------------------------------------------------------------------
__device__ __forceinline__ void mlp_layer128(const short* __restrict__ src,
                                             const short* __restrict__ WT,
                                             const float* __restrict__ bias,
                                             short* __restrict__ dst,
                                             int w, int lane)
{
    const int wm = w >> 1, wn = w & 1;   // 2x2 wave grid, 64x64 tile each
    const int lr = lane & 15;
    const int lk = (lane >> 4) << 3;
    f32x4 acc[4][4] = {};
#pragma unroll
    for (int ks = 0; ks < 4; ++ks) {
        const int kb = ks * 32 + lk;
        s16x8 a[4], b[4];
#pragma unroll
        for (int rf = 0; rf < 4; ++rf) {
            int row = wm * 64 + rf * 16 + lr;
            int off = (row * 256 + kb * 2) ^ ((row & 7) << 4);
            a[rf] = *(const s16x8*)((const char*)src + off);
        }
#pragma unroll
        for (int cf = 0; cf < 4; ++cf) {
            int n = wn * 64 + cf * 16 + lr;
            b[cf] = *(const s16x8*)(WT + n * 128 + kb);
        }
#pragma unroll
        for (int rf = 0; rf < 4; ++rf)
#pragma unroll
            for (int cf = 0; cf < 4; ++cf)
                acc[rf][cf] = __builtin_amdgcn_mfma_f32_16x16x32_bf16(a[rf], b[cf], acc[rf][cf], 0, 0, 0);
    }
#pragma unroll
    for (int cf = 0; cf < 4; ++cf) {
        int col = wn * 64 + cf * 16 + lr;
        float bv = bias[col];
#pragma unroll
        for (int rf = 0; rf < 4; ++rf) {
#pragma unroll
            for (int q = 0; q < 4; ++q) {
                int row = wm * 64 + rf * 16 + ((lane >> 4) << 2) + q;
                float v = fmaxf(acc[rf][cf][q] + bv, 0.f);
                int off = (row * 256 + col * 2) ^ ((row & 7) << 4);
                *(short*)((char*)dst + off) = f2bf(v);
            }
        }
    }
}

__global__ __launch_bounds__(256, 2)
void k_phase1(const float* __restrict__ x,
              const float* __restrict__ W1, const float* __restrict__ b1,
              const short* __restrict__ W2T, const float* __restrict__ b2,
              const short* __restrict__ W3T, const float* __restrict__ b3,
              const float* __restrict__ W4T, const float* __restrict__ b4,
              float* __restrict__ out_buf, float* __restrict__ diagpart)
{
    __shared__ short hA[128 * 128];
    __shared__ short hB[128 * 128];
    const int t = threadIdx.x;
    const int lane = t & 63;
    const int w = t >> 6;
    const int m0 = blockIdx.x * 128;

    // ---- L1 (VALU, K=4): features -> 128, relu, bf16 into swizzled hA ----
    {
        int row = t & 127;
        int half = t >> 7;               // wave-uniform
        int m = m0 + row;
        int bc = m / 4032;
        int rem = m - bc * 4032;
        int r = rem >> 6;
        int k = rem & 63;
        int j = (k + r + 1) & 63;
        const float* xb = x + bc * 4096;
        float f0 = xb[k * 64 + k];
        float f1 = xb[k * 64 + j];
        float f2 = xb[j * 64 + k];
        float f3 = xb[j * 64 + j];
        int e0 = half * 64;
#pragma unroll
        for (int eo = 0; eo < 64; eo += 8) {
            s16x8 pack;
#pragma unroll
            for (int q = 0; q < 8; ++q) {
                int e = e0 + eo + q;
                float acc = b1[e] + f0 * W1[e] + f1 * W1[128 + e] + f2 * W1[256 + e] + f3 * W1[384 + e];
                pack[q] = f2bf(fmaxf(acc, 0.f));
            }
            int off = (row * 256 + (e0 + eo) * 2) ^ ((row & 7) << 4);
            *(s16x8*)((char*)hA + off) = pack;
        }
    }
    __syncthreads();

    // ---- L2, L3 (MFMA) ----
    mlp_layer128(hA, W2T, b2, hB, w, lane);
    __syncthreads();
    mlp_layer128(hB, W3T, b3, hA, w, lane);
    __syncthreads();

    // ---- L4 (VALU, N=2): dot(h3[row], W4T[sel]) ----
    {
        int sel = t >> 7;                // wave-uniform -> scalar W4T loads
        int row = t & 127;
        const float* wv = W4T + sel * 128;
        float acc = b4[sel];
#pragma unroll
        for (int kc = 0; kc < 128; kc += 8) {
            int off = (row * 256 + kc * 2) ^ ((row & 7) << 4);
            s16x8 hv = *(const s16x8*)((const char*)hA + off);
#pragma unroll
            for (int q = 0; q < 8; ++q)
                acc += bf2f(hv[q]) * wv[kc + q];
        }
        int m = m0 + row;
        int bc = m / 4032;
        int rem = m - bc * 4032;
        int r = rem >> 6;
        int k = rem & 63;
        if (sel) {
            int j = (k + r + 1) & 63;
            out_buf[bc * 4096 + k * 64 + j] = acc;   // off-diagonal scatter
        } else {
            diagpart[m] = acc;                        // h0 for diag reduction
        }
    }
}

// ---------------------------------------------------------------------------
// Diag reduction: out[bc][k][k] = mean_r h0[bc][r][k]
// ---------------------------------------------------------------------------
__global__ void k_diag(const float* __restrict__ diagpart, float* __restrict__ out_buf)
{
    int tid = blockIdx.x * 256 + threadIdx.x;   // 16384 = 256bc * 64k
    int bc = tid >> 6;
    int k = tid & 63;
    const float* p = diagpart + bc * 4032 + k;
    float s = 0.f;
    for (int r = 0; r < 63; ++r) s += p[r * 64];
    out_buf[bc * 4096 + k * 65] = s * (1.0f / 63.0f);
}

// ---------------------------------------------------------------------------
// Channel MLP layer: Y[16384, N] = act(X[16384, K] @ W[K,N] + b)
// SRC_MODE 0: X bf16 row-major [M][K]; SRC_MODE 1: X = out_buf fp32 [b][c][nm]
// DST_MODE 0: bf16 [M][N]; DST_MODE 1: final fp32 d_out [b][h][nm]
// ---------------------------------------------------------------------------
template<int K, int N, bool RELU, int SRC_MODE, int DST_MODE>
__global__ __launch_bounds__(256, 2)
void k_chan(const void* __restrict__ srcv, const short* __restrict__ WT,
            const float* __restrict__ bias, void* __restrict__ dstv)
{
    __shared__ short A[64 * K];
    const int t = threadIdx.x;
    const int lane = t & 63;
    const int w = t >> 6;
    const int m0 = blockIdx.x * 64;

    if (SRC_MODE == 0) {
        const short* src = (const short*)srcv;
        for (int idx = t * 8; idx < 64 * K; idx += 256 * 8) {
            int row = idx / K;
            int kk = idx - row * K;
            s16x8 v = *(const s16x8*)(src + (size_t)m0 * K + idx);
            int off = (row * (K * 2) + kk * 2) ^ ((row & 7) << 4);
            *(s16x8*)((char*)A + off) = v;
        }
    } else {
        const float* src = (const float*)srcv;   // out_buf, K == 64
        int b = m0 >> 12;
        int nm0 = m0 & 4095;
        int c = t >> 2;
        int no = (t & 3) * 16;
        const float* p = src + (size_t)(b * 64 + c) * 4096 + nm0 + no;
#pragma unroll
        for (int q = 0; q < 16; ++q) {
            int row = no + q;
            int off = (row * (K * 2) + c * 2) ^ ((row & 7) << 4);
            *(short*)((char*)A + off) = f2bf(p[q]);
        }
    }
    __syncthreads();

    constexpr int CFW = (N >= 64) ? (N / 64) : 1;
    constexpr int RFW = (N >= 64) ? 4 : 2;
    const int cfb = (N >= 64) ? w * CFW : (w & 1);
    const int rfb = (N >= 64) ? 0 : (w >> 1) * RFW;
    const int lr = lane & 15;
    const int lk = (lane >> 4) << 3;

    f32x4 acc[RFW][CFW] = {};
#pragma unroll
    for (int ks = 0; ks < K / 32; ++ks) {
        const int kb = ks * 32 + lk;
        s16x8 a[RFW], b[CFW];
#pragma unroll
        for (int rf = 0; rf < RFW; ++rf) {
            int row = (rfb + rf) * 16 + lr;
            int off = (row * (K * 2) + kb * 2) ^ ((row & 7) << 4);
            a[rf] = *(const s16x8*)((const char*)A + off);
        }
#pragma unroll
        for (int cf = 0; cf < CFW; ++cf) {
            int n = (cfb + cf) * 16 + lr;
            b[cf] = *(const s16x8*)(WT + (size_t)n * K + kb);
        }
#pragma unroll
        for (int rf = 0; rf < RFW; ++rf)
#pragma unroll
            for (int cf = 0; cf < CFW; ++cf)
                acc[rf][cf] = __builtin_amdgcn_mfma_f32_16x16x32_bf16(a[rf], b[cf], acc[rf][cf], 0, 0, 0);
    }

#pragma unroll
    for (int cf = 0; cf < CFW; ++cf) {
        int col = (cfb + cf) * 16 + lr;
        float bv = bias[col];
#pragma unroll
        for (int rf = 0; rf < RFW; ++rf) {
            int rbase = (rfb + rf) * 16 + ((lane >> 4) << 2);
#pragma unroll
            for (int q = 0; q < 4; ++q) {
                int row = rbase + q;
                float v = acc[rf][cf][q] + bv;
                if (RELU) v = fmaxf(v, 0.f);
                if (DST_MODE == 0) {
                    ((short*)dstv)[(size_t)(m0 + row) * N + col] = f2bf(v);
                } else {
                    int b2_ = m0 >> 12;
                    int nm = (m0 & 4095) + row;
                    ((float*)dstv)[(size_t)(b2_ * 32 + col) * 4096 + nm] = v;
                }
            }
        }
    }
}

// ---------------------------------------------------------------------------
extern "C" void kernel_launch(void* const* d_in, const int* in_sizes, int n_in,
                              void* d_out, int out_size, void* d_ws, size_t ws_size,
                              hipStream_t stream)
{
    const float* x   = (const float*)d_in[0];
    const float* W1  = (const float*)d_in[1];
    const float* b1  = (const float*)d_in[2];
    const float* W2  = (const float*)d_in[3];
    const float* b2  = (const float*)d_in[4];
    const float* W3  = (const float*)d_in[5];
    const float* b3  = (const float*)d_in[6];
    const float* W4  = (const float*)d_in[7];
    const float* b4  = (const float*)d_in[8];
    const float* Wc1 = (const float*)d_in[9];
    const float* bc1 = (const float*)d_in[10];
    const float* Wc2 = (const float*)d_in[11];
    const float* bc2 = (const float*)d_in[12];
    const float* Wc3 = (const float*)d_in[13];
    const float* bc3 = (const float*)d_in[14];
    const float* Wc4 = (const float*)d_in[15];
    const float* bc4 = (const float*)d_in[16];
    float* out = (float*)d_out;

    char* ws = (char*)d_ws;
    // layout: [0,4M) out_buf | [4M,12M) region A | [12M,20M) region B | [20M,..) weights
    float* out_buf  = (float*)(ws);
    float* diagpart = (float*)(ws + (4u << 20));   // region A (first 4MB)
    short* y1       = (short*)(ws + (12u << 20));  // region B (4MB used)
    short* y2       = (short*)(ws + (4u << 20));   // region A reuse (8MB)
    short* y3       = (short*)(ws + (12u << 20));  // region B reuse (8MB)

    size_t off = 20u << 20;
    short* W2T  = (short*)(ws + off); off += 16384 * 2;
    short* W3T  = (short*)(ws + off); off += 16384 * 2;
    short* Wc1T = (short*)(ws + off); off += 8192 * 2;
    short* Wc2T = (short*)(ws + off); off += 32768 * 2;
    short* Wc3T = (short*)(ws + off); off += 65536 * 2;
    short* Wc4T = (short*)(ws + off); off += 8192 * 2;
    float* W4T  = (float*)(ws + off); off += 256 * 4;

    k_prep<<<256, 256, 0, stream>>>(W2, W3, W4, Wc1, Wc2, Wc3, Wc4,
                                    W2T, W3T, W4T, Wc1T, Wc2T, Wc3T, Wc4T);
    k_phase1<<<8064, 256, 0, stream>>>(x, W1, b1, W2T, b2, W3T, b3, W4T, b4,
                                       out_buf, diagpart);
    k_diag<<<64, 256, 0, stream>>>(diagpart, out_buf);
    k_chan< 64, 128, true, 1, 0><<<256, 256, 0, stream>>>(out_buf, Wc1T, bc1, y1);
    k_chan<128, 256, true, 0, 0><<<256, 256, 0, stream>>>(y1, Wc2T, bc2, y2);
    k_chan<256, 256, true, 0, 0><<<256, 256, 0, stream>>>(y2, Wc3T, bc3, y3);
    k_chan<256,  32, false, 0, 1><<<256, 256, 0, stream>>>(y3, Wc4T, bc4, out);
}

// Round 6
// 278.933 us; speedup vs baseline: 1.3316x; 1.3316x over previous
//
#include <hip/hip_runtime.h>

typedef __attribute__((ext_vector_type(4))) float f32x4;
typedef __attribute__((ext_vector_type(8))) short s16x8;
typedef __attribute__((ext_vector_type(4))) short s16x4;

__device__ __forceinline__ short f2bf(float f) {          // RNE (weights, once)
    unsigned u = __builtin_bit_cast(unsigned, f);
    u += 0x7fffu + ((u >> 16) & 1u);
    return (short)(u >> 16);
}
__device__ __forceinline__ short f2bf_fast(float f) {     // round-half-up (activations)
    unsigned u = __builtin_bit_cast(unsigned, f);
    return (short)((u + 0x8000u) >> 16);
}

// ---------------------------------------------------------------------------
// Weight prep: transpose to [n][k] bf16 (contiguous k for MFMA fragments).
// ---------------------------------------------------------------------------
__global__ void k_prep(const float* __restrict__ W2, const float* __restrict__ W3,
                       const float* __restrict__ W4,
                       const float* __restrict__ Wc1, const float* __restrict__ Wc2,
                       const float* __restrict__ Wc3, const float* __restrict__ Wc4,
                       short* __restrict__ W2T, short* __restrict__ W3T,
                       float* __restrict__ W4T,
                       short* __restrict__ Wc1T, short* __restrict__ Wc2T,
                       short* __restrict__ Wc3T, short* __restrict__ Wc4T)
{
    int tid = blockIdx.x * 256 + threadIdx.x;   // 65536 total
    if (tid < 16384) {  // W2T/W3T: [n<128][k<128]
        int n = tid >> 7, k = tid & 127;
        W2T[tid] = f2bf(W2[k * 128 + n]);
        W3T[tid] = f2bf(W3[k * 128 + n]);
    }
    if (tid < 256) {    // W4T: [s<2][k<128] fp32
        int s = tid >> 7, k = tid & 127;
        W4T[tid] = W4[k * 2 + s];
    }
    if (tid < 8192) {   // Wc1T: [n<128][c<64]
        int n = tid >> 6, c = tid & 63;
        Wc1T[tid] = f2bf(Wc1[c * 128 + n]);
    }
    if (tid < 32768) {  // Wc2T: [n<256][k<128]
        int n = tid >> 7, k = tid & 127;
        Wc2T[tid] = f2bf(Wc2[k * 256 + n]);
    }
    if (tid < 65536) {  // Wc3T: [n<256][k<256]
        int n = tid >> 8, k = tid & 255;
        Wc3T[tid] = f2bf(Wc3[k * 256 + n]);
    }
    if (tid < 8192) {   // Wc4T: [n<32][k<256]
        int n = tid >> 8, k = tid & 255;
        Wc4T[tid] = f2bf(Wc4[k * 32 + n]);
    }
}

// ---------------------------------------------------------------------------
// Phase-1: 64 edge-rows per block (block b: bc=b/63 uniform, r=b%63 uniform).
// L1 VALU -> hA; L2 MFMA (swapped, n-partitioned waves) -> hB; L3 MFMA + L4
// in-register + shfl/LDS reduce -> scatter bf16 out_buf + fp32 diagpart.
// ---------------------------------------------------------------------------
__global__ __launch_bounds__(256, 4)
void k_phase1(const float* __restrict__ x,
              const float* __restrict__ W1, const float* __restrict__ b1,
              const short* __restrict__ W2T, const float* __restrict__ b2,
              const short* __restrict__ W3T, const float* __restrict__ b3,
              const float* __restrict__ W4T, const float* __restrict__ b4,
              short* __restrict__ outb, float* __restrict__ diagpart)
{
    __shared__ short hA[64 * 128];            // 16 KB, rows swizzled ^((row&7)<<4)
    __shared__ short hB[64 * 128];            // 16 KB
    __shared__ float red[4][4][16][2];        // 2 KB cross-wave L4 partials
    const int t = threadIdx.x;
    const int lane = t & 63;
    const int w = t >> 6;
    const int lr = lane & 15;
    const int hi = lane >> 4;
    const int b = blockIdx.x;
    const int bc = b / 63;                    // block-uniform
    const int r  = b - bc * 63;               // block-uniform

    // ---- L1 (VALU): 64 rows x 128 feats; thread = (row kk, 32-feat quarter) ----
    {
        const int kk = t & 63;
        const int e0 = __builtin_amdgcn_readfirstlane((t >> 6) * 32);  // wave-uniform -> s_loads
        const int jj = (kk + r + 1) & 63;
        const float* xb = x + bc * 4096;
        float f0 = xb[kk * 65], f1 = xb[kk * 64 + jj];
        float f2 = xb[jj * 64 + kk], f3 = xb[jj * 65];
#pragma unroll
        for (int eo = 0; eo < 32; eo += 8) {
            s16x8 pk;
#pragma unroll
            for (int q = 0; q < 8; ++q) {
                int e = e0 + eo + q;
                float a = fmaf(f3, W1[384 + e], fmaf(f2, W1[256 + e],
                          fmaf(f1, W1[128 + e], fmaf(f0, W1[e], b1[e]))));
                pk[q] = f2bf_fast(fmaxf(a, 0.f));
            }
            int off = (kk * 256 + (e0 + eo) * 2) ^ ((kk & 7) << 4);
            *(s16x8*)((char*)hA + off) = pk;
        }
    }
    __syncthreads();

    const int n0 = w * 32;   // each wave owns 32 output features (no W redundancy)

    // ---- L2 (MFMA, swapped: D[n][m]) ----
    f32x4 acc[4][2] = {};
#pragma unroll
    for (int ks = 0; ks < 4; ++ks) {
        const int kb = ks * 32 + hi * 8;
        s16x8 aw[2], bh[4];
#pragma unroll
        for (int nf = 0; nf < 2; ++nf)
            aw[nf] = *(const s16x8*)(W2T + (n0 + nf * 16 + lr) * 128 + kb);
#pragma unroll
        for (int mf = 0; mf < 4; ++mf) {
            int off = ((mf * 16 + lr) * 256 + kb * 2) ^ ((lr & 7) << 4);
            bh[mf] = *(const s16x8*)((const char*)hA + off);
        }
#pragma unroll
        for (int mf = 0; mf < 4; ++mf)
#pragma unroll
            for (int nf = 0; nf < 2; ++nf)
                acc[mf][nf] = __builtin_amdgcn_mfma_f32_16x16x32_bf16(aw[nf], bh[mf], acc[mf][nf], 0, 0, 0);
    }
    {   // epilogue: bias+relu+bf16, packed 8B LDS stores
        f32x4 bv[2];
#pragma unroll
        for (int nf = 0; nf < 2; ++nf)
            bv[nf] = *(const f32x4*)(b2 + n0 + nf * 16 + 4 * hi);
#pragma unroll
        for (int mf = 0; mf < 4; ++mf) {
            int m = mf * 16 + lr;
#pragma unroll
            for (int nf = 0; nf < 2; ++nf) {
                s16x4 pk;
#pragma unroll
                for (int q = 0; q < 4; ++q)
                    pk[q] = f2bf_fast(fmaxf(acc[mf][nf][q] + bv[nf][q], 0.f));
                int off = (m * 256 + (n0 + nf * 16 + 4 * hi) * 2) ^ ((m & 7) << 4);
                *(s16x4*)((char*)hB + off) = pk;
            }
        }
    }
    __syncthreads();

    // ---- L3 (MFMA) + L4 fused in-register ----
    f32x4 acc3[4][2] = {};
#pragma unroll
    for (int ks = 0; ks < 4; ++ks) {
        const int kb = ks * 32 + hi * 8;
        s16x8 aw[2], bh[4];
#pragma unroll
        for (int nf = 0; nf < 2; ++nf)
            aw[nf] = *(const s16x8*)(W3T + (n0 + nf * 16 + lr) * 128 + kb);
#pragma unroll
        for (int mf = 0; mf < 4; ++mf) {
            int off = ((mf * 16 + lr) * 256 + kb * 2) ^ ((lr & 7) << 4);
            bh[mf] = *(const s16x8*)((const char*)hB + off);
        }
#pragma unroll
        for (int mf = 0; mf < 4; ++mf)
#pragma unroll
            for (int nf = 0; nf < 2; ++nf)
                acc3[mf][nf] = __builtin_amdgcn_mfma_f32_16x16x32_bf16(aw[nf], bh[mf], acc3[mf][nf], 0, 0, 0);
    }
    {
        f32x4 bv[2], w40[2], w41[2];
#pragma unroll
        for (int nf = 0; nf < 2; ++nf) {
            bv[nf]  = *(const f32x4*)(b3 + n0 + nf * 16 + 4 * hi);
            w40[nf] = *(const f32x4*)(W4T + n0 + nf * 16 + 4 * hi);
            w41[nf] = *(const f32x4*)(W4T + 128 + n0 + nf * 16 + 4 * hi);
        }
#pragma unroll
        for (int mf = 0; mf < 4; ++mf) {
            float s0 = 0.f, s1 = 0.f;
#pragma unroll
            for (int nf = 0; nf < 2; ++nf)
#pragma unroll
                for (int q = 0; q < 4; ++q) {
                    float h = fmaxf(acc3[mf][nf][q] + bv[nf][q], 0.f);
                    s0 = fmaf(h, w40[nf][q], s0);
                    s1 = fmaf(h, w41[nf][q], s1);
                }
            s0 += __shfl_xor(s0, 16, 64); s0 += __shfl_xor(s0, 32, 64);
            s1 += __shfl_xor(s1, 16, 64); s1 += __shfl_xor(s1, 32, 64);
            if (hi == 0) { red[w][mf][lr][0] = s0; red[w][mf][lr][1] = s1; }
        }
    }
    __syncthreads();
    if (t < 128) {
        int k = t & 63, s = t >> 6;
        int mf = k >> 4, lr2 = k & 15;
        float v = red[0][mf][lr2][s] + red[1][mf][lr2][s]
                + red[2][mf][lr2][s] + red[3][mf][lr2][s] + b4[s];
        if (s) {
            int jj = (k + r + 1) & 63;
            outb[bc * 4096 + k * 64 + jj] = f2bf(v);    // off-diagonal scatter (bf16)
        } else {
            diagpart[b * 64 + k] = v;                   // h0 for diag mean (fp32)
        }
    }
}

// ---------------------------------------------------------------------------
// Diag: out[bc][k][k] = mean_r h0[bc][r][k]; coalesced rows, LDS reduce.
// ---------------------------------------------------------------------------
__global__ void k_diag(const float* __restrict__ diagpart, short* __restrict__ outb)
{
    __shared__ float rds[256];
    const int t = threadIdx.x, bcq = blockIdx.x;
    const int kx = t & 63, q = t >> 6;
    const float* p = diagpart + bcq * 4032 + kx;
    int r0 = q * 16, r1 = (r0 + 16 < 63) ? r0 + 16 : 63;
    float s = 0.f;
    for (int rr = r0; rr < r1; ++rr) s += p[rr * 64];
    rds[t] = s;
    __syncthreads();
    if (t < 64) {
        float v = (rds[t] + rds[t + 64] + rds[t + 128] + rds[t + 192]) * (1.0f / 63.0f);
        outb[bcq * 4096 + t * 65] = f2bf(v);
    }
}

// ---------------------------------------------------------------------------
// Channel MLP layer, 32-row x NT-col tiles, n-partitioned waves, swapped MFMA.
// SRC 0: bf16 [M][K] row-major.  SRC 1: out_buf bf16 [4][64][4096] (transpose).
// DST 0: bf16 [M][N_OUT].        DST 1: final fp32 [4][32][4096].
// ---------------------------------------------------------------------------
template<int K, int NT, int NWN, int N_OUT, bool RELU, int SRC, int DST>
__global__ __launch_bounds__(256, 4)
void k_chan(const void* __restrict__ srcv, const short* __restrict__ WT,
            const float* __restrict__ bias, void* __restrict__ dstv)
{
    constexpr int MF = (NWN == 4) ? 2 : 1;
    constexpr int NF = NT / (16 * NWN);
    constexpr int KS = K / 32;
    __shared__ short A[32 * K];
    const int t = threadIdx.x, lane = t & 63, w = t >> 6;
    const int lr = lane & 15, hi = lane >> 4;
    const int m0 = blockIdx.x * 32;
    const int col0 = blockIdx.y * NT;
    const int wn = w & (NWN - 1);
    const int wm = w >> ((NWN == 4) ? 2 : 1);
    const int n0 = col0 + wn * 16 * NF;

    if (SRC == 0) {
        const short* src = (const short*)srcv;
#pragma unroll
        for (int i = t * 8; i < 32 * K; i += 2048) {
            int row = i / K, kk2 = i - row * K;
            s16x8 v = *(const s16x8*)(src + (size_t)m0 * K + i);
            int off = (row * (K * 2) + kk2 * 2) ^ ((row & 7) << 4);
            *(s16x8*)((char*)A + off) = v;
        }
    } else {
        const short* src = (const short*)srcv;          // [4][64][4096] bf16
        int bb = blockIdx.x >> 7;
        int nm0 = (blockIdx.x & 127) * 32;
        int c = t & 63, rq = t >> 6;
        s16x8 v = *(const s16x8*)(src + ((size_t)(bb * 64 + c)) * 4096 + nm0 + rq * 8);
#pragma unroll
        for (int q = 0; q < 8; ++q) {
            int row = rq * 8 + q;
            int off = (row * (K * 2) + c * 2) ^ ((row & 7) << 4);
            *(short*)((char*)A + off) = v[q];
        }
    }
    __syncthreads();

    f32x4 acc[MF][NF] = {};
#pragma unroll
    for (int ks = 0; ks < KS; ++ks) {
        const int kb = ks * 32 + hi * 8;
        s16x8 aw[NF], bh[MF];
#pragma unroll
        for (int nf = 0; nf < NF; ++nf)
            aw[nf] = *(const s16x8*)(WT + (size_t)(n0 + nf * 16 + lr) * K + kb);
#pragma unroll
        for (int mf = 0; mf < MF; ++mf) {
            int row = (wm * MF + mf) * 16 + lr;
            int off = (row * (K * 2) + kb * 2) ^ ((lr & 7) << 4);
            bh[mf] = *(const s16x8*)((const char*)A + off);
        }
#pragma unroll
        for (int mf = 0; mf < MF; ++mf)
#pragma unroll
            for (int nf = 0; nf < NF; ++nf)
                acc[mf][nf] = __builtin_amdgcn_mfma_f32_16x16x32_bf16(aw[nf], bh[mf], acc[mf][nf], 0, 0, 0);
    }

    f32x4 bv[NF];
#pragma unroll
    for (int nf = 0; nf < NF; ++nf)
        bv[nf] = *(const f32x4*)(bias + n0 + nf * 16 + 4 * hi);
#pragma unroll
    for (int mf = 0; mf < MF; ++mf) {
        int mrow = (wm * MF + mf) * 16 + lr;
#pragma unroll
        for (int nf = 0; nf < NF; ++nf) {
            if (DST == 0) {
                s16x4 pk;
#pragma unroll
                for (int q = 0; q < 4; ++q) {
                    float v2 = acc[mf][nf][q] + bv[nf][q];
                    if (RELU) v2 = fmaxf(v2, 0.f);
                    pk[q] = f2bf_fast(v2);
                }
                *(s16x4*)((short*)dstv + (size_t)(m0 + mrow) * N_OUT + n0 + nf * 16 + 4 * hi) = pk;
            } else {
                int bb = blockIdx.x >> 7;
                int nm = (blockIdx.x & 127) * 32 + mrow;
#pragma unroll
                for (int q = 0; q < 4; ++q) {
                    int n = n0 + nf * 16 + 4 * hi + q;
                    ((float*)dstv)[(size_t)(bb * 32 + n) * 4096 + nm] = acc[mf][nf][q] + bv[nf][q];
                }
            }
        }
    }
}

// ---------------------------------------------------------------------------
extern "C" void kernel_launch(void* const* d_in, const int* in_sizes, int n_in,
                              void* d_out, int out_size, void* d_ws, size_t ws_size,
                              hipStream_t stream)
{
    const float* x   = (const float*)d_in[0];
    const float* W1  = (const float*)d_in[1];
    const float* b1  = (const float*)d_in[2];
    const float* W2  = (const float*)d_in[3];
    const float* b2  = (const float*)d_in[4];
    const float* W3  = (const float*)d_in[5];
    const float* b3  = (const float*)d_in[6];
    const float* W4  = (const float*)d_in[7];
    const float* b4  = (const float*)d_in[8];
    const float* Wc1 = (const float*)d_in[9];
    const float* bc1 = (const float*)d_in[10];
    const float* Wc2 = (const float*)d_in[11];
    const float* bc2 = (const float*)d_in[12];
    const float* Wc3 = (const float*)d_in[13];
    const float* bc3 = (const float*)d_in[14];
    const float* Wc4 = (const float*)d_in[15];
    const float* bc4 = (const float*)d_in[16];
    float* out = (float*)d_out;

    char* ws = (char*)d_ws;
    // [0,8M) y3 | [8M,10M) outb | [10M,14M) diag | [8M,16M) y2 (reuses dead
    // outb+diag after c1) | [16M,20M) y1 | [20M,~20.3M) weights
    short* y3       = (short*)(ws);
    short* outb     = (short*)(ws + (8u  << 20));
    float* diagpart = (float*)(ws + (10u << 20));
    short* y2       = (short*)(ws + (8u  << 20));
    short* y1       = (short*)(ws + (16u << 20));

    size_t off = 20u << 20;
    short* W2T  = (short*)(ws + off); off += 16384 * 2;
    short* W3T  = (short*)(ws + off); off += 16384 * 2;
    short* Wc1T = (short*)(ws + off); off += 8192 * 2;
    short* Wc2T = (short*)(ws + off); off += 32768 * 2;
    short* Wc3T = (short*)(ws + off); off += 65536 * 2;
    short* Wc4T = (short*)(ws + off); off += 8192 * 2;
    float* W4T  = (float*)(ws + off); off += 256 * 4;

    k_prep<<<256, 256, 0, stream>>>(W2, W3, W4, Wc1, Wc2, Wc3, Wc4,
                                    W2T, W3T, W4T, Wc1T, Wc2T, Wc3T, Wc4T);
    k_phase1<<<16128, 256, 0, stream>>>(x, W1, b1, W2T, b2, W3T, b3, W4T, b4,
                                        outb, diagpart);
    k_diag<<<256, 256, 0, stream>>>(diagpart, outb);
    k_chan< 64, 128, 4, 128, true,  1, 0><<<dim3(512, 1), 256, 0, stream>>>(outb, Wc1T, bc1, y1);
    k_chan<128, 128, 4, 256, true,  0, 0><<<dim3(512, 2), 256, 0, stream>>>(y1, Wc2T, bc2, y2);
    k_chan<256, 128, 4, 256, true,  0, 0><<<dim3(512, 2), 256, 0, stream>>>(y2, Wc3T, bc3, y3);
    k_chan<256,  32, 2,  32, false, 0, 1><<<dim3(512, 1), 256, 0, stream>>>(y3, Wc4T, bc4, out);
}

// Round 7
// 253.580 us; speedup vs baseline: 1.4647x; 1.1000x over previous
//
#include <hip/hip_runtime.h>

typedef __attribute__((ext_vector_type(4))) float f32x4;
typedef __attribute__((ext_vector_type(8))) short s16x8;
typedef __attribute__((ext_vector_type(4))) short s16x4;

__device__ __forceinline__ short f2bf(float f) {          // RNE (weights, once)
    unsigned u = __builtin_bit_cast(unsigned, f);
    u += 0x7fffu + ((u >> 16) & 1u);
    return (short)(u >> 16);
}
__device__ __forceinline__ short f2bf_fast(float f) {     // round-half-up (activations)
    unsigned u = __builtin_bit_cast(unsigned, f);
    return (short)((u + 0x8000u) >> 16);
}

// ---------------------------------------------------------------------------
// Weight prep: transpose to [n][k] bf16 (contiguous k for MFMA fragments).
// ---------------------------------------------------------------------------
__global__ void k_prep(const float* __restrict__ W2, const float* __restrict__ W3,
                       const float* __restrict__ W4,
                       const float* __restrict__ Wc1, const float* __restrict__ Wc2,
                       const float* __restrict__ Wc3, const float* __restrict__ Wc4,
                       short* __restrict__ W2T, short* __restrict__ W3T,
                       float* __restrict__ W4T,
                       short* __restrict__ Wc1T, short* __restrict__ Wc2T,
                       short* __restrict__ Wc3T, short* __restrict__ Wc4T)
{
    int tid = blockIdx.x * 256 + threadIdx.x;   // 65536 total
    if (tid < 16384) {  // W2T/W3T: [n<128][k<128]
        int n = tid >> 7, k = tid & 127;
        W2T[tid] = f2bf(W2[k * 128 + n]);
        W3T[tid] = f2bf(W3[k * 128 + n]);
    }
    if (tid < 256) {    // W4T: [s<2][k<128] fp32
        int s = tid >> 7, k = tid & 127;
        W4T[tid] = W4[k * 2 + s];
    }
    if (tid < 8192) {   // Wc1T: [n<128][c<64]
        int n = tid >> 6, c = tid & 63;
        Wc1T[tid] = f2bf(Wc1[c * 128 + n]);
    }
    if (tid < 32768) {  // Wc2T: [n<256][k<128]
        int n = tid >> 7, k = tid & 127;
        Wc2T[tid] = f2bf(Wc2[k * 256 + n]);
    }
    if (tid < 65536) {  // Wc3T: [n<256][k<256]
        int n = tid >> 8, k = tid & 255;
        Wc3T[tid] = f2bf(Wc3[k * 256 + n]);
    }
    if (tid < 8192) {   // Wc4T: [n<32][k<256]
        int n = tid >> 8, k = tid & 255;
        Wc4T[tid] = f2bf(Wc4[k * 32 + n]);
    }
}

// ---------------------------------------------------------------------------
// Phase-1: 64 edge-rows per block. All W2T/W3T MFMA fragments preloaded into
// registers at entry (latency hidden under L1 VALU) -> MFMA phases have zero
// global loads in the hot loops.
// ---------------------------------------------------------------------------
__global__ __launch_bounds__(256, 4)
void k_phase1(const float* __restrict__ x,
              const float* __restrict__ W1, const float* __restrict__ b1,
              const short* __restrict__ W2T, const float* __restrict__ b2,
              const short* __restrict__ W3T, const float* __restrict__ b3,
              const float* __restrict__ W4T, const float* __restrict__ b4,
              short* __restrict__ outb, float* __restrict__ diagpart)
{
    __shared__ short hA[64 * 128];            // 16 KB, rows swizzled ^((row&7)<<4)
    __shared__ short hB[64 * 128];            // 16 KB
    __shared__ float red[4][4][16][2];        // 2 KB cross-wave L4 partials
    const int t = threadIdx.x;
    const int lane = t & 63;
    const int w = t >> 6;
    const int lr = lane & 15;
    const int hi = lane >> 4;
    const int b = blockIdx.x;
    const int bc = b / 63;                    // block-uniform
    const int r  = b - bc * 63;               // block-uniform

    const int n0 = w * 32;   // each wave owns 32 output features

    // ---- preload ALL L2/L3 weight fragments (issued before L1 compute) ----
    s16x8 aw2[4][2], aw3[4][2];
#pragma unroll
    for (int ks = 0; ks < 4; ++ks)
#pragma unroll
        for (int nf = 0; nf < 2; ++nf) {
            aw2[ks][nf] = *(const s16x8*)(W2T + (n0 + nf * 16 + lr) * 128 + ks * 32 + hi * 8);
            aw3[ks][nf] = *(const s16x8*)(W3T + (n0 + nf * 16 + lr) * 128 + ks * 32 + hi * 8);
        }

    // ---- L1 (VALU): 64 rows x 128 feats; thread = (row kk, 32-feat quarter) ----
    {
        const int kk = t & 63;
        const int e0 = __builtin_amdgcn_readfirstlane((t >> 6) * 32);  // wave-uniform -> s_loads
        const int jj = (kk + r + 1) & 63;
        const float* xb = x + bc * 4096;
        float f0 = xb[kk * 65], f1 = xb[kk * 64 + jj];
        float f2 = xb[jj * 64 + kk], f3 = xb[jj * 65];
#pragma unroll
        for (int eo = 0; eo < 32; eo += 8) {
            s16x8 pk;
#pragma unroll
            for (int q = 0; q < 8; ++q) {
                int e = e0 + eo + q;
                float a = fmaf(f3, W1[384 + e], fmaf(f2, W1[256 + e],
                          fmaf(f1, W1[128 + e], fmaf(f0, W1[e], b1[e]))));
                pk[q] = f2bf_fast(fmaxf(a, 0.f));
            }
            int off = (kk * 256 + (e0 + eo) * 2) ^ ((kk & 7) << 4);
            *(s16x8*)((char*)hA + off) = pk;
        }
    }
    __syncthreads();

    // ---- L2 (MFMA, swapped: D[n][m]) ----
    f32x4 acc[4][2] = {};
#pragma unroll
    for (int ks = 0; ks < 4; ++ks) {
        const int kb = ks * 32 + hi * 8;
        s16x8 bh[4];
#pragma unroll
        for (int mf = 0; mf < 4; ++mf) {
            int off = ((mf * 16 + lr) * 256 + kb * 2) ^ ((lr & 7) << 4);
            bh[mf] = *(const s16x8*)((const char*)hA + off);
        }
#pragma unroll
        for (int mf = 0; mf < 4; ++mf)
#pragma unroll
            for (int nf = 0; nf < 2; ++nf)
                acc[mf][nf] = __builtin_amdgcn_mfma_f32_16x16x32_bf16(aw2[ks][nf], bh[mf], acc[mf][nf], 0, 0, 0);
    }
    {   // epilogue: bias+relu+bf16, packed 8B LDS stores
        f32x4 bv[2];
#pragma unroll
        for (int nf = 0; nf < 2; ++nf)
            bv[nf] = *(const f32x4*)(b2 + n0 + nf * 16 + 4 * hi);
#pragma unroll
        for (int mf = 0; mf < 4; ++mf) {
            int m = mf * 16 + lr;
#pragma unroll
            for (int nf = 0; nf < 2; ++nf) {
                s16x4 pk;
#pragma unroll
                for (int q = 0; q < 4; ++q)
                    pk[q] = f2bf_fast(fmaxf(acc[mf][nf][q] + bv[nf][q], 0.f));
                int off = (m * 256 + (n0 + nf * 16 + 4 * hi) * 2) ^ ((m & 7) << 4);
                *(s16x4*)((char*)hB + off) = pk;
            }
        }
    }
    __syncthreads();

    // ---- L3 (MFMA) + L4 fused in-register ----
    f32x4 acc3[4][2] = {};
#pragma unroll
    for (int ks = 0; ks < 4; ++ks) {
        const int kb = ks * 32 + hi * 8;
        s16x8 bh[4];
#pragma unroll
        for (int mf = 0; mf < 4; ++mf) {
            int off = ((mf * 16 + lr) * 256 + kb * 2) ^ ((lr & 7) << 4);
            bh[mf] = *(const s16x8*)((const char*)hB + off);
        }
#pragma unroll
        for (int mf = 0; mf < 4; ++mf)
#pragma unroll
            for (int nf = 0; nf < 2; ++nf)
                acc3[mf][nf] = __builtin_amdgcn_mfma_f32_16x16x32_bf16(aw3[ks][nf], bh[mf], acc3[mf][nf], 0, 0, 0);
    }
    {
        f32x4 bv[2], w40[2], w41[2];
#pragma unroll
        for (int nf = 0; nf < 2; ++nf) {
            bv[nf]  = *(const f32x4*)(b3 + n0 + nf * 16 + 4 * hi);
            w40[nf] = *(const f32x4*)(W4T + n0 + nf * 16 + 4 * hi);
            w41[nf] = *(const f32x4*)(W4T + 128 + n0 + nf * 16 + 4 * hi);
        }
#pragma unroll
        for (int mf = 0; mf < 4; ++mf) {
            float s0 = 0.f, s1 = 0.f;
#pragma unroll
            for (int nf = 0; nf < 2; ++nf)
#pragma unroll
                for (int q = 0; q < 4; ++q) {
                    float h = fmaxf(acc3[mf][nf][q] + bv[nf][q], 0.f);
                    s0 = fmaf(h, w40[nf][q], s0);
                    s1 = fmaf(h, w41[nf][q], s1);
                }
            s0 += __shfl_xor(s0, 16, 64); s0 += __shfl_xor(s0, 32, 64);
            s1 += __shfl_xor(s1, 16, 64); s1 += __shfl_xor(s1, 32, 64);
            if (hi == 0) { red[w][mf][lr][0] = s0; red[w][mf][lr][1] = s1; }
        }
    }
    __syncthreads();
    if (t < 128) {
        int k = t & 63, s = t >> 6;
        int mf = k >> 4, lr2 = k & 15;
        float v = red[0][mf][lr2][s] + red[1][mf][lr2][s]
                + red[2][mf][lr2][s] + red[3][mf][lr2][s] + b4[s];
        if (s) {
            int jj = (k + r + 1) & 63;
            outb[bc * 4096 + k * 64 + jj] = f2bf(v);    // off-diagonal scatter (bf16)
        } else {
            diagpart[b * 64 + k] = v;                   // h0 for diag mean (fp32)
        }
    }
}

// ---------------------------------------------------------------------------
// Diag: out[bc][k][k] = mean_r h0[bc][r][k]; coalesced rows, LDS reduce.
// ---------------------------------------------------------------------------
__global__ void k_diag(const float* __restrict__ diagpart, short* __restrict__ outb)
{
    __shared__ float rds[256];
    const int t = threadIdx.x, bcq = blockIdx.x;
    const int kx = t & 63, q = t >> 6;
    const float* p = diagpart + bcq * 4032 + kx;
    int r0 = q * 16, r1 = (r0 + 16 < 63) ? r0 + 16 : 63;
    float s = 0.f;
    for (int rr = r0; rr < r1; ++rr) s += p[rr * 64];
    rds[t] = s;
    __syncthreads();
    if (t < 64) {
        float v = (rds[t] + rds[t + 64] + rds[t + 128] + rds[t + 192]) * (1.0f / 63.0f);
        outb[bcq * 4096 + t * 65] = f2bf(v);
    }
}

// ---------------------------------------------------------------------------
// One inner layer of the fused channel MLP: [32 rows][K] bf16 (LDS, swizzled)
// -> [32 rows][N] bf16 (LDS, swizzled). 4 waves split N; each wave owns N/4.
// ---------------------------------------------------------------------------
template<int K, int N, bool RELU>
__device__ __forceinline__ void chan_layer(const short* src, const short* __restrict__ WT,
                                           const float* __restrict__ bias, short* dst,
                                           int w, int lr, int hi)
{
    constexpr int NF = N / 64;
    constexpr int KS = K / 32;
    const int n0 = w * (16 * NF);
    f32x4 acc[2][NF] = {};
#pragma unroll
    for (int ks = 0; ks < KS; ++ks) {
        const int kb = ks * 32 + hi * 8;
        s16x8 aw[NF], bh[2];
#pragma unroll
        for (int nf = 0; nf < NF; ++nf)
            aw[nf] = *(const s16x8*)(WT + (n0 + nf * 16 + lr) * K + kb);
#pragma unroll
        for (int mf = 0; mf < 2; ++mf) {
            int off = ((mf * 16 + lr) * (K * 2) + kb * 2) ^ ((lr & 7) << 4);
            bh[mf] = *(const s16x8*)((const char*)src + off);
        }
#pragma unroll
        for (int mf = 0; mf < 2; ++mf)
#pragma unroll
            for (int nf = 0; nf < NF; ++nf)
                acc[mf][nf] = __builtin_amdgcn_mfma_f32_16x16x32_bf16(aw[nf], bh[mf], acc[mf][nf], 0, 0, 0);
    }
    f32x4 bv[NF];
#pragma unroll
    for (int nf = 0; nf < NF; ++nf)
        bv[nf] = *(const f32x4*)(bias + n0 + nf * 16 + 4 * hi);
#pragma unroll
    for (int mf = 0; mf < 2; ++mf) {
        int m = mf * 16 + lr;
#pragma unroll
        for (int nf = 0; nf < NF; ++nf) {
            s16x4 pk;
#pragma unroll
            for (int q = 0; q < 4; ++q) {
                float v = acc[mf][nf][q] + bv[nf][q];
                if (RELU) v = fmaxf(v, 0.f);
                pk[q] = f2bf_fast(v);
            }
            int off = (m * (N * 2) + (n0 + nf * 16 + 4 * hi) * 2) ^ ((m & 7) << 4);
            *(s16x4*)((char*)dst + off) = pk;
        }
    }
}

// ---------------------------------------------------------------------------
// Fused channel MLP: 64->128->256->256->32, all intermediates LDS-resident.
// Block = 32 nm-rows of one batch b. Grid 512. bufA/bufB ping-pong (16KB each).
// ---------------------------------------------------------------------------
__global__ __launch_bounds__(256, 4)
void k_chanfused(const short* __restrict__ outb,
                 const short* __restrict__ Wc1T, const float* __restrict__ bc1,
                 const short* __restrict__ Wc2T, const float* __restrict__ bc2,
                 const short* __restrict__ Wc3T, const float* __restrict__ bc3,
                 const short* __restrict__ Wc4T, const float* __restrict__ bc4,
                 float* __restrict__ out)
{
    __shared__ short bufA[32 * 256];   // 16 KB: A0 [32][64] -> h2 [32][256]
    __shared__ short bufB[32 * 256];   // 16 KB: h1 [32][128] -> h3 [32][256]
    const int t = threadIdx.x, lane = t & 63, w = t >> 6;
    const int lr = lane & 15, hi = lane >> 4;
    const int bb = blockIdx.x >> 7;
    const int nm0 = (blockIdx.x & 127) * 32;

    // stage A0: [32 rows][64 c], row stride 128B, swizzled
    {
        int c = t & 63, rq = t >> 6;
        s16x8 v = *(const s16x8*)(outb + ((size_t)(bb * 64 + c)) * 4096 + nm0 + rq * 8);
#pragma unroll
        for (int q = 0; q < 8; ++q) {
            int row = rq * 8 + q;
            int off = (row * 128 + c * 2) ^ ((row & 7) << 4);
            *(short*)((char*)bufA + off) = v[q];
        }
    }
    __syncthreads();
    chan_layer< 64, 128, true>(bufA, Wc1T, bc1, bufB, w, lr, hi);
    __syncthreads();
    chan_layer<128, 256, true>(bufB, Wc2T, bc2, bufA, w, lr, hi);
    __syncthreads();
    chan_layer<256, 256, true>(bufA, Wc3T, bc3, bufB, w, lr, hi);
    __syncthreads();

    // c4: K=256, N=32, fp32 out. wn=w&1 picks 16 feats, wm=w>>1 picks 16 rows.
    {
        const int wn = w & 1, wm = w >> 1;
        const int n0 = wn * 16;
        f32x4 acc = {};
#pragma unroll
        for (int ks = 0; ks < 8; ++ks) {
            const int kb = ks * 32 + hi * 8;
            s16x8 aw = *(const s16x8*)(Wc4T + (n0 + lr) * 256 + kb);
            int off = ((wm * 16 + lr) * 512 + kb * 2) ^ ((lr & 7) << 4);
            s16x8 bh = *(const s16x8*)((const char*)bufB + off);
            acc = __builtin_amdgcn_mfma_f32_16x16x32_bf16(aw, bh, acc, 0, 0, 0);
        }
        f32x4 bv = *(const f32x4*)(bc4 + n0 + 4 * hi);
        const int m = wm * 16 + lr;
#pragma unroll
        for (int q = 0; q < 4; ++q) {
            int n = n0 + 4 * hi + q;
            out[((size_t)(bb * 32 + n)) * 4096 + nm0 + m] = acc[q] + bv[q];
        }
    }
}

// ---------------------------------------------------------------------------
extern "C" void kernel_launch(void* const* d_in, const int* in_sizes, int n_in,
                              void* d_out, int out_size, void* d_ws, size_t ws_size,
                              hipStream_t stream)
{
    const float* x   = (const float*)d_in[0];
    const float* W1  = (const float*)d_in[1];
    const float* b1  = (const float*)d_in[2];
    const float* W2  = (const float*)d_in[3];
    const float* b2  = (const float*)d_in[4];
    const float* W3  = (const float*)d_in[5];
    const float* b3  = (const float*)d_in[6];
    const float* W4  = (const float*)d_in[7];
    const float* b4  = (const float*)d_in[8];
    const float* Wc1 = (const float*)d_in[9];
    const float* bc1 = (const float*)d_in[10];
    const float* Wc2 = (const float*)d_in[11];
    const float* bc2 = (const float*)d_in[12];
    const float* Wc3 = (const float*)d_in[13];
    const float* bc3 = (const float*)d_in[14];
    const float* Wc4 = (const float*)d_in[15];
    const float* bc4 = (const float*)d_in[16];
    float* out = (float*)d_out;

    char* ws = (char*)d_ws;
    // [0,2M) outb bf16 | [2M,8M) diagpart | [8M,...) weights
    short* outb     = (short*)(ws);
    float* diagpart = (float*)(ws + (2u << 20));

    size_t off = 8u << 20;
    short* W2T  = (short*)(ws + off); off += 16384 * 2;
    short* W3T  = (short*)(ws + off); off += 16384 * 2;
    short* Wc1T = (short*)(ws + off); off += 8192 * 2;
    short* Wc2T = (short*)(ws + off); off += 32768 * 2;
    short* Wc3T = (short*)(ws + off); off += 65536 * 2;
    short* Wc4T = (short*)(ws + off); off += 8192 * 2;
    float* W4T  = (float*)(ws + off); off += 256 * 4;

    k_prep<<<256, 256, 0, stream>>>(W2, W3, W4, Wc1, Wc2, Wc3, Wc4,
                                    W2T, W3T, W4T, Wc1T, Wc2T, Wc3T, Wc4T);
    k_phase1<<<16128, 256, 0, stream>>>(x, W1, b1, W2T, b2, W3T, b3, W4T, b4,
                                        outb, diagpart);
    k_diag<<<256, 256, 0, stream>>>(diagpart, outb);
    k_chanfused<<<512, 256, 0, stream>>>(outb, Wc1T, bc1, Wc2T, bc2,
                                         Wc3T, bc3, Wc4T, bc4, out);
}